// Round 5
// baseline (193.396 us; speedup 1.0000x reference)
//
#include <hip/hip_runtime.h>
#include <hip/hip_bf16.h>

// SelectiveDense: out[b,g,u] = relu(sum_k x[b, idx[g,k]] * kern[g,k,u] + bias[u])
// B=8192 D=4096 G=256 K=32 U=64. f32 in/out, bf16 MFMA compute.
// R4: R3 + NON-TEMPORAL stores. Theory: write-back L2/L3 evicts our 8192 row-
//     streams in set/LRU order, scrambling the DRAM address stream; nt stores
//     stream past the caches preserving the sequential per-window order.

#define B_ 8192
#define D_ 4096
#define G_ 256
#define K_ 32
#define U_ 64

typedef short v8s __attribute__((ext_vector_type(8)));     // 8 bf16 (4 VGPRs) MFMA A/B frag
typedef float f32x4 __attribute__((ext_vector_type(4)));   // MFMA C/D frag

__device__ __forceinline__ unsigned short f2bf(float f) {
    unsigned int u = __float_as_uint(f);
    u = (u + 0x7FFFu + ((u >> 16) & 1u)) >> 16;   // round-to-nearest-even
    return (unsigned short)u;
}

// Pre-pass: kernels f32 [G][K][U] -> bf16 frag layout [G][4 utiles][64 lanes][8]
// MFMA B operand: lane l holds B[k=(l>>4)*8+j][col=u_local=l&15]
__global__ void prep_kb(const float* __restrict__ kern, unsigned short* __restrict__ kb) {
    int tid = blockIdx.x * blockDim.x + threadIdx.x;   // over G*K*U
    if (tid >= G_ * K_ * U_) return;
    int u = tid & (U_ - 1);
    int k = (tid >> 6) & (K_ - 1);
    int g = tid >> 11;
    int t = u >> 4;                       // u-tile 0..3
    int lane = ((k >> 3) << 4) | (u & 15);
    int j = k & 7;
    kb[((((g << 2) + t) << 6 | lane) << 3) | j] = f2bf(kern[tid]);
}

#define XS 4100   // LDS row stride (ushorts): bank shift 2/row -> gather ~conflict-free

__global__ void __launch_bounds__(512) sdense(
        const float* __restrict__ x, const unsigned short* __restrict__ kb,
        const float* __restrict__ bias, const int* __restrict__ idx,
        float* __restrict__ out) {
    extern __shared__ unsigned short lx[];   // [16][XS] bf16 x rows
    const int tid = threadIdx.x;
    const int b0 = blockIdx.x << 4;
    const int lane = tid & 63;
    const int w = tid >> 6;               // wave 0..7

    // ---- stage 16 rows of x (f32 -> bf16): wave w -> rows 2w, 2w+1 ----
    {
        const int row = (w << 1) + (lane >> 5);
        const int l32 = lane & 31;
        const float* xr = x + (size_t)(b0 + row) * D_;
        unsigned short* lr = lx + row * XS;
        #pragma unroll
        for (int i = 0; i < 16; ++i) {
            int col = (i << 8) + (l32 << 3);       // 8 floats / lane / iter
            float4 v0 = *(const float4*)(xr + col);
            float4 v1 = *(const float4*)(xr + col + 4);
            union { unsigned short u[8]; v8s v; } st;
            st.u[0] = f2bf(v0.x); st.u[1] = f2bf(v0.y);
            st.u[2] = f2bf(v0.z); st.u[3] = f2bf(v0.w);
            st.u[4] = f2bf(v1.x); st.u[5] = f2bf(v1.y);
            st.u[6] = f2bf(v1.z); st.u[7] = f2bf(v1.w);
            *(v8s*)(lr + col) = st.v;              // 16B ds_write
        }
    }
    __syncthreads();

    // ---- super-iter: wave w covers g in [32q+4w, 32q+4w+4); block window 32 g's ----
    const int grp = lane >> 4;            // 0..3
    const int l15 = lane & 15;
    const int rowb = l15 * XS;            // A-operand: lane gathers x row b=l15
    const int kk0 = grp << 3;

    float bias_v[4];
    #pragma unroll
    for (int t = 0; t < 4; ++t) bias_v[t] = bias[(t << 4) + l15];

    const v8s* kbv = (const v8s*)kb;

    for (int q = 0; q < 8; ++q) {
        const int g0 = (q << 5) + (w << 2);   // 32q + 4w

        // idx for 4 g's (L2-hot)
        int4 ia[4], ibb[4];
        #pragma unroll
        for (int j = 0; j < 4; ++j) {
            const int4* ip = (const int4*)(idx + ((g0 + j) << 5) + kk0);
            ia[j] = ip[0]; ibb[j] = ip[1];
        }
        // kb frags for 4 g's (L2-hot)
        v8s kf[4][4];
        #pragma unroll
        for (int j = 0; j < 4; ++j) {
            const v8s* kg = kbv + ((g0 + j) << 8) + lane;
            kf[j][0] = kg[0]; kf[j][1] = kg[64]; kf[j][2] = kg[128]; kf[j][3] = kg[192];
        }

        // gather + MFMA, accumulate 4 g's of output in VGPRs
        f32x4 acc[4][4];
        #pragma unroll
        for (int j = 0; j < 4; ++j) {
            union { unsigned short u[8]; v8s v; } A;  // A[m=b=l15][k=grp*8+jj]
            A.u[0] = lx[rowb + ia[j].x];  A.u[1] = lx[rowb + ia[j].y];
            A.u[2] = lx[rowb + ia[j].z];  A.u[3] = lx[rowb + ia[j].w];
            A.u[4] = lx[rowb + ibb[j].x]; A.u[5] = lx[rowb + ibb[j].y];
            A.u[6] = lx[rowb + ibb[j].z]; A.u[7] = lx[rowb + ibb[j].w];
            f32x4 z = {0.f, 0.f, 0.f, 0.f};
            #pragma unroll
            for (int t = 0; t < 4; ++t)
                acc[j][t] = __builtin_amdgcn_mfma_f32_16x16x32_bf16(A.v, kf[j][t], z, 0, 0, 0);
        }

        // store phase: r-outer; per row, 16 sequential 64B segments = 1KB contiguous.
        // NON-TEMPORAL: stream past L2/L3 so DRAM sees issue order, not eviction order.
        #pragma unroll
        for (int r = 0; r < 4; ++r) {
            float* obr = out + (size_t)(b0 + (grp << 2) + r) * (G_ * U_) + (g0 << 6) + l15;
            #pragma unroll
            for (int j = 0; j < 4; ++j) {
                #pragma unroll
                for (int t = 0; t < 4; ++t) {
                    float v = acc[j][t][r] + bias_v[t];
                    v = v > 0.f ? v : 0.f;
                    __builtin_nontemporal_store(v, obr + (j << 6) + (t << 4));
                }
            }
        }

        // raw barrier keeps the 8 waves' g-windows aligned (no vmcnt drain)
        __builtin_amdgcn_s_barrier();
    }
}

extern "C" void kernel_launch(void* const* d_in, const int* in_sizes, int n_in,
                              void* d_out, int out_size, void* d_ws, size_t ws_size,
                              hipStream_t stream) {
    const float* x    = (const float*)d_in[0];
    const float* kern = (const float*)d_in[1];
    const float* bias = (const float*)d_in[2];
    const int*   idx  = (const int*)d_in[3];
    float* out = (float*)d_out;
    unsigned short* kb = (unsigned short*)d_ws;   // 1 MiB bf16 kernel frags

    prep_kb<<<(G_ * K_ * U_ + 255) / 256, 256, 0, stream>>>(kern, kb);
    sdense<<<B_ / 16, 512, 16 * XS * sizeof(unsigned short), stream>>>(x, kb, bias, idx, out);
}

// Round 6
// 169.860 us; speedup vs baseline: 1.1386x; 1.1386x over previous
//
#include <hip/hip_runtime.h>
#include <hip/hip_bf16.h>

// SelectiveDense: out[b,g,u] = relu(sum_k x[b, idx[g,k]] * kern[g,k,u] + bias[u])
// B=8192 D=4096 G=256 K=32 U=64. f32 in/out, bf16 MFMA compute.
// R5: (A) u-within-tile remap (u = 4*col + t) -> float4 (dwordx4) output stores,
//         guaranteeing full 128B-line writes (kills suspected L2 write-allocate RMW).
//     (B) QG=8 g's accumulated per store burst -> 2KB contiguous per row per visit.
//     nt stores reverted (R4 regression).

#define B_ 8192
#define D_ 4096
#define G_ 256
#define K_ 32
#define U_ 64
#define QG 8

typedef short v8s __attribute__((ext_vector_type(8)));     // 8 bf16 (4 VGPRs) MFMA A/B frag
typedef float f32x4 __attribute__((ext_vector_type(4)));   // MFMA C/D frag

__device__ __forceinline__ unsigned short f2bf(float f) {
    unsigned int u = __float_as_uint(f);
    u = (u + 0x7FFFu + ((u >> 16) & 1u)) >> 16;   // round-to-nearest-even
    return (unsigned short)u;
}

// Pre-pass: kernels f32 [G][K][U] -> bf16 frag layout [G][4 tiles][64 lanes][8]
// MFMA B operand for tile t: lane l holds B[k=(l>>4)*8+j][col=l&15], col maps to u=4*col+t.
__global__ void prep_kb(const float* __restrict__ kern, unsigned short* __restrict__ kb) {
    int tid = blockIdx.x * blockDim.x + threadIdx.x;   // over G*K*U
    if (tid >= G_ * K_ * U_) return;
    int u = tid & (U_ - 1);
    int k = (tid >> 6) & (K_ - 1);
    int g = tid >> 11;
    int t = u & 3;                        // u-within-quad -> tile index
    int col = u >> 2;                     // quad index -> MFMA column
    int lane = ((k >> 3) << 4) | col;
    int j = k & 7;
    kb[((((g << 2) + t) << 6 | lane) << 3) | j] = f2bf(kern[tid]);
}

#define XS 4100   // LDS row stride (ushorts): bank shift 2/row -> gather ~conflict-free

__global__ void __launch_bounds__(512) sdense(
        const float* __restrict__ x, const unsigned short* __restrict__ kb,
        const float* __restrict__ bias, const int* __restrict__ idx,
        float* __restrict__ out) {
    extern __shared__ unsigned short lx[];   // [16][XS] bf16 x rows
    const int tid = threadIdx.x;
    const int b0 = blockIdx.x << 4;
    const int lane = tid & 63;
    const int w = tid >> 6;               // wave 0..7

    // ---- stage 16 rows of x (f32 -> bf16): wave w -> rows 2w, 2w+1 ----
    {
        const int row = (w << 1) + (lane >> 5);
        const int l32 = lane & 31;
        const float* xr = x + (size_t)(b0 + row) * D_;
        unsigned short* lr = lx + row * XS;
        #pragma unroll
        for (int i = 0; i < 16; ++i) {
            int col = (i << 8) + (l32 << 3);       // 8 floats / lane / iter
            float4 v0 = *(const float4*)(xr + col);
            float4 v1 = *(const float4*)(xr + col + 4);
            union { unsigned short u[8]; v8s v; } st;
            st.u[0] = f2bf(v0.x); st.u[1] = f2bf(v0.y);
            st.u[2] = f2bf(v0.z); st.u[3] = f2bf(v0.w);
            st.u[4] = f2bf(v1.x); st.u[5] = f2bf(v1.y);
            st.u[6] = f2bf(v1.z); st.u[7] = f2bf(v1.w);
            *(v8s*)(lr + col) = st.v;              // 16B ds_write
        }
    }
    __syncthreads();

    // ---- super-iter: wave w covers g in [64q+8w, 64q+8w+8); block window 64 g's ----
    const int grp = lane >> 4;            // 0..3
    const int l15 = lane & 15;
    const int rowb = l15 * XS;            // A-operand: lane gathers x row b=l15
    const int kk0 = grp << 3;

    const float4 bias_v = *(const float4*)(bias + (l15 << 2));  // u = 4*l15 + 0..3

    const v8s* kbv = (const v8s*)kb;

    for (int q = 0; q < 4; ++q) {
        const int g0 = (q << 6) + (w << 3);   // 64q + 8w

        f32x4 acc[QG][4];
        #pragma unroll
        for (int j = 0; j < QG; ++j) {
            const int g = g0 + j;
            const int4* ip = (const int4*)(idx + (g << 5) + kk0);
            int4 ia = ip[0], ib = ip[1];
            const v8s* kg = kbv + (g << 8) + lane;
            v8s k0 = kg[0], k1 = kg[64], k2 = kg[128], k3 = kg[192];

            union { unsigned short u[8]; v8s v; } A;  // A[m=b=l15][k=grp*8+jj]
            A.u[0] = lx[rowb + ia.x]; A.u[1] = lx[rowb + ia.y];
            A.u[2] = lx[rowb + ia.z]; A.u[3] = lx[rowb + ia.w];
            A.u[4] = lx[rowb + ib.x]; A.u[5] = lx[rowb + ib.y];
            A.u[6] = lx[rowb + ib.z]; A.u[7] = lx[rowb + ib.w];

            f32x4 z = {0.f, 0.f, 0.f, 0.f};
            acc[j][0] = __builtin_amdgcn_mfma_f32_16x16x32_bf16(A.v, k0, z, 0, 0, 0);
            acc[j][1] = __builtin_amdgcn_mfma_f32_16x16x32_bf16(A.v, k1, z, 0, 0, 0);
            acc[j][2] = __builtin_amdgcn_mfma_f32_16x16x32_bf16(A.v, k2, z, 0, 0, 0);
            acc[j][3] = __builtin_amdgcn_mfma_f32_16x16x32_bf16(A.v, k3, z, 0, 0, 0);
        }

        // store phase: r-outer; per row, 8 sequential dwordx4 instrs = 2KB contiguous
        // per wave-visit (lane l15 owns u=4*l15..4*l15+3 -> full-line 16B/lane stores).
        #pragma unroll
        for (int r = 0; r < 4; ++r) {
            float* obr = out + (size_t)(b0 + (grp << 2) + r) * (G_ * U_)
                             + (g0 << 6) + (l15 << 2);
            #pragma unroll
            for (int j = 0; j < QG; ++j) {
                float4 v;
                v.x = acc[j][0][r] + bias_v.x;
                v.y = acc[j][1][r] + bias_v.y;
                v.z = acc[j][2][r] + bias_v.z;
                v.w = acc[j][3][r] + bias_v.w;
                v.x = v.x > 0.f ? v.x : 0.f;
                v.y = v.y > 0.f ? v.y : 0.f;
                v.z = v.z > 0.f ? v.z : 0.f;
                v.w = v.w > 0.f ? v.w : 0.f;
                *(float4*)(obr + (j << 6)) = v;
            }
        }

        // raw barrier keeps the 8 waves' g-windows aligned (no vmcnt drain)
        __builtin_amdgcn_s_barrier();
    }
}

extern "C" void kernel_launch(void* const* d_in, const int* in_sizes, int n_in,
                              void* d_out, int out_size, void* d_ws, size_t ws_size,
                              hipStream_t stream) {
    const float* x    = (const float*)d_in[0];
    const float* kern = (const float*)d_in[1];
    const float* bias = (const float*)d_in[2];
    const int*   idx  = (const int*)d_in[3];
    float* out = (float*)d_out;
    unsigned short* kb = (unsigned short*)d_ws;   // 1 MiB bf16 kernel frags

    prep_kb<<<(G_ * K_ * U_ + 255) / 256, 256, 0, stream>>>(kern, kb);
    sdense<<<B_ / 16, 512, 16 * XS * sizeof(unsigned short), stream>>>(x, kb, bias, idx, out);
}